// Round 1
// baseline (401.176 us; speedup 1.0000x reference)
//
#include <hip/hip_runtime.h>
#include <math.h>

#define N 4096
#define D 768
#define MARGIN 1.0f
#define EPS_D 1e-12f

#define TI 128
#define TJ 128
#define BK 16

// ---------------- Kernel 1: row L2-normalize ----------------
__global__ __launch_bounds__(256) void normalize_kernel(const float* __restrict__ x,
                                                        float* __restrict__ e,
                                                        float* __restrict__ sq) {
    const int row = blockIdx.x;
    const int tid = threadIdx.x;
    const float* xr = x + (size_t)row * D;
    float* er = e + (size_t)row * D;

    // 768 = 3 * 256
    float v0 = xr[tid];
    float v1 = xr[tid + 256];
    float v2 = xr[tid + 512];
    float s = v0 * v0 + v1 * v1 + v2 * v2;

    #pragma unroll
    for (int off = 32; off; off >>= 1) s += __shfl_down(s, off, 64);

    __shared__ float wsum[4];
    if ((tid & 63) == 0) wsum[tid >> 6] = s;
    __syncthreads();
    float tot = wsum[0] + wsum[1] + wsum[2] + wsum[3];

    float norm = sqrtf(tot);
    float scale = 1.0f / fmaxf(norm, 1e-12f);

    er[tid]       = v0 * scale;
    er[tid + 256] = v1 * scale;
    er[tid + 512] = v2 * scale;
    if (tid == 0) sq[row] = tot * scale * scale;
}

// ---------------- Kernel 2: init per-row accumulators ----------------
__global__ void init_kernel(unsigned* __restrict__ ap_bits, unsigned* __restrict__ an_bits) {
    int i = blockIdx.x * 256 + threadIdx.x;
    if (i < N) {
        ap_bits[i] = 0u;            // float 0.0  (masked max init; valid handled separately)
        an_bits[i] = 0x7f800000u;   // +inf       (masked min init)
    }
}

// ---------------- Kernel 3: fused Gram + batch-hard mining ----------------
// grid (N/TI, N/TJ) = (32, 32); block 256 threads; 8x8 register tile.
__global__ __launch_bounds__(256) void mine_kernel(const float* __restrict__ e,
                                                   const float* __restrict__ sq,
                                                   const int* __restrict__ labels,
                                                   unsigned* __restrict__ ap_bits,
                                                   unsigned* __restrict__ an_bits) {
    __shared__ float As[BK][TI];  // k-major: As[kk][row]
    __shared__ float Bs[BK][TJ];

    const int tid = threadIdx.x;
    const int i0 = blockIdx.x * TI;
    const int j0 = blockIdx.y * TJ;
    const int tr = tid >> 4;      // 0..15 -> rows i0 + tr*8 .. +7
    const int tc = tid & 15;      // 0..15 -> cols j0 + tc*8 .. +7

    int   mylab[8];
    float mysq[8];
    #pragma unroll
    for (int m = 0; m < 8; m++) {
        int r = i0 + tr * 8 + m;
        mylab[m] = labels[r];
        mysq[m]  = sq[r];
    }

    float acc[8][8];
    #pragma unroll
    for (int m = 0; m < 8; m++)
        #pragma unroll
        for (int n = 0; n < 8; n++) acc[m][n] = 0.f;

    for (int k0 = 0; k0 < D; k0 += BK) {
        __syncthreads();
        // stage A (TIxBK) and B (TJxBK), transposed to k-major in LDS.
        #pragma unroll
        for (int p = 0; p < 2; p++) {
            int linear = p * 256 + tid;   // 0..511
            int row = linear >> 2;        // 0..127
            int c4  = linear & 3;         // 0..3 -> k offset c4*4
            const float4 va = *(const float4*)(e + (size_t)(i0 + row) * D + k0 + c4 * 4);
            As[c4 * 4 + 0][row] = va.x;
            As[c4 * 4 + 1][row] = va.y;
            As[c4 * 4 + 2][row] = va.z;
            As[c4 * 4 + 3][row] = va.w;
            const float4 vb = *(const float4*)(e + (size_t)(j0 + row) * D + k0 + c4 * 4);
            Bs[c4 * 4 + 0][row] = vb.x;
            Bs[c4 * 4 + 1][row] = vb.y;
            Bs[c4 * 4 + 2][row] = vb.z;
            Bs[c4 * 4 + 3][row] = vb.w;
        }
        __syncthreads();

        #pragma unroll
        for (int kk = 0; kk < BK; kk++) {
            float4 a0 = *(const float4*)&As[kk][tr * 8];
            float4 a1 = *(const float4*)&As[kk][tr * 8 + 4];
            float4 b0 = *(const float4*)&Bs[kk][tc * 8];
            float4 b1 = *(const float4*)&Bs[kk][tc * 8 + 4];
            float a[8] = {a0.x, a0.y, a0.z, a0.w, a1.x, a1.y, a1.z, a1.w};
            float b[8] = {b0.x, b0.y, b0.z, b0.w, b1.x, b1.y, b1.z, b1.w};
            #pragma unroll
            for (int m = 0; m < 8; m++)
                #pragma unroll
                for (int n = 0; n < 8; n++) acc[m][n] += a[m] * b[n];
        }
    }

    // epilogue: dist + masked max/min
    float ap[8], an[8];
    #pragma unroll
    for (int m = 0; m < 8; m++) { ap[m] = -INFINITY; an[m] = INFINITY; }

    #pragma unroll
    for (int n = 0; n < 8; n++) {
        int j = j0 + tc * 8 + n;
        int lj = labels[j];
        float sj = sq[j];
        #pragma unroll
        for (int m = 0; m < 8; m++) {
            float d2 = mysq[m] + sj - 2.0f * acc[m][n];
            float dist = sqrtf(fmaxf(d2, 0.f) + (float)EPS_D);
            int i = i0 + tr * 8 + m;
            if (mylab[m] == lj) {
                if (i != j) ap[m] = fmaxf(ap[m], dist);
            } else {
                an[m] = fminf(an[m], dist);
            }
        }
    }

    // reduce across the 16 tc-lanes (consecutive lanes within a wave)
    #pragma unroll
    for (int m = 0; m < 8; m++) {
        float a_ = ap[m], n_ = an[m];
        #pragma unroll
        for (int off = 8; off; off >>= 1) {
            a_ = fmaxf(a_, __shfl_down(a_, off, 16));
            n_ = fminf(n_, __shfl_down(n_, off, 16));
        }
        if (tc == 0) {
            int r = i0 + tr * 8 + m;
            if (a_ > -INFINITY) atomicMax(&ap_bits[r], __float_as_uint(a_));
            if (n_ <  INFINITY) atomicMin(&an_bits[r], __float_as_uint(n_));
        }
    }
}

// ---------------- Kernel 4: finalize ----------------
__global__ __launch_bounds__(256) void finalize_kernel(const unsigned* __restrict__ ap_bits,
                                                       const unsigned* __restrict__ an_bits,
                                                       const int* __restrict__ labels,
                                                       float* __restrict__ out) {
    __shared__ int cnt[4];
    __shared__ float red[8];
    int tid = threadIdx.x;
    if (tid < 4) cnt[tid] = 0;
    __syncthreads();

    int local[4] = {0, 0, 0, 0};
    for (int i = tid; i < N; i += 256) local[labels[i] & 3]++;
    #pragma unroll
    for (int c = 0; c < 4; c++) atomicAdd(&cnt[c], local[c]);
    __syncthreads();

    float sum = 0.f, nv = 0.f;
    for (int i = tid; i < N; i += 256) {
        int l = labels[i] & 3;
        if (cnt[l] >= 2) {
            nv += 1.f;
            float apv = __uint_as_float(ap_bits[i]);
            float anv = __uint_as_float(an_bits[i]);
            if (anv < 3.0e38f) {
                sum += fmaxf(apv - anv + MARGIN, 0.f);
            }
            // else: no negatives anywhere -> max(ap - inf + margin, 0) = 0
        }
    }

    #pragma unroll
    for (int off = 32; off; off >>= 1) {
        sum += __shfl_down(sum, off, 64);
        nv  += __shfl_down(nv,  off, 64);
    }
    int w = tid >> 6;
    if ((tid & 63) == 0) { red[w] = sum; red[4 + w] = nv; }
    __syncthreads();
    if (tid == 0) {
        float s = red[0] + red[1] + red[2] + red[3];
        float n = red[4] + red[5] + red[6] + red[7];
        out[0] = s / fmaxf(n, 1.f);
    }
}

// ---------------- Launch ----------------
extern "C" void kernel_launch(void* const* d_in, const int* in_sizes, int n_in,
                              void* d_out, int out_size, void* d_ws, size_t ws_size,
                              hipStream_t stream) {
    const float* x = (const float*)d_in[0];
    const int* labels = (const int*)d_in[1];
    float* out = (float*)d_out;

    float* e = (float*)d_ws;
    float* sq = e + (size_t)N * D;
    unsigned* ap_bits = (unsigned*)(sq + N);
    unsigned* an_bits = ap_bits + N;

    normalize_kernel<<<N, 256, 0, stream>>>(x, e, sq);
    init_kernel<<<N / 256, 256, 0, stream>>>(ap_bits, an_bits);
    mine_kernel<<<dim3(N / TI, N / TJ), 256, 0, stream>>>(e, sq, labels, ap_bits, an_bits);
    finalize_kernel<<<1, 256, 0, stream>>>(ap_bits, an_bits, labels, out);
}

// Round 2
// 135.949 us; speedup vs baseline: 2.9509x; 2.9509x over previous
//
#include <hip/hip_runtime.h>
#include <math.h>

#define N 4096
#define D 768
#define MARGIN 1.0f

typedef _Float16 half8 __attribute__((ext_vector_type(8)));
typedef float f32x4 __attribute__((ext_vector_type(4)));

__device__ __forceinline__ void gl2lds16(const void* g, void* l) {
    __builtin_amdgcn_global_load_lds((const __attribute__((address_space(1))) void*)g,
                                     (__attribute__((address_space(3))) void*)l, 16, 0, 0);
}

// ---------------- Kernel 1: row L2-normalize (fp32 in -> f16 out) + init ----
__global__ __launch_bounds__(256) void normalize_kernel(const float* __restrict__ x,
                                                        _Float16* __restrict__ e,
                                                        float* __restrict__ sq,
                                                        unsigned* __restrict__ ap_bits,
                                                        unsigned* __restrict__ an_bits) {
    const int row = blockIdx.x;
    const int tid = threadIdx.x;
    const float* xr = x + (size_t)row * D;
    _Float16* er = e + (size_t)row * D;

    // 768 = 3 * 256
    float v0 = xr[tid];
    float v1 = xr[tid + 256];
    float v2 = xr[tid + 512];
    float s = v0 * v0 + v1 * v1 + v2 * v2;

    #pragma unroll
    for (int off = 32; off; off >>= 1) s += __shfl_down(s, off, 64);

    __shared__ float wsum[4];
    if ((tid & 63) == 0) wsum[tid >> 6] = s;
    __syncthreads();
    float tot = wsum[0] + wsum[1] + wsum[2] + wsum[3];

    float norm = sqrtf(tot);
    float scale = 1.0f / fmaxf(norm, 1e-12f);

    er[tid]       = (_Float16)(v0 * scale);
    er[tid + 256] = (_Float16)(v1 * scale);
    er[tid + 512] = (_Float16)(v2 * scale);
    if (tid == 0) {
        sq[row] = tot * scale * scale;     // == ||e_row||^2 (~1.0), fp32
        ap_bits[row] = 0u;                 // float 0.0 (max init)
        an_bits[row] = 0x7f800000u;        // +inf      (min init)
    }
}

// ---------------- Kernel 2: MFMA Gram + batch-hard mining (triangular) -----
// 1D grid of 528 blocks -> upper-triangular (bi <= bj) 128x128 tiles.
// 256 threads = 4 waves, each wave owns a 64x64 quadrant (4x4 MFMA tiles).
__global__ __launch_bounds__(256) void mine_kernel(const _Float16* __restrict__ e,
                                                   const float* __restrict__ sq,
                                                   const int* __restrict__ labels,
                                                   unsigned* __restrict__ ap_bits,
                                                   unsigned* __restrict__ an_bits) {
    __shared__ unsigned short S[8192];   // A tile: ushort [0,4096); B tile: [4096,8192)

    // map linear block -> (bi, bj), bi <= bj
    int bi = 0, rem = blockIdx.x;
    while (rem >= 32 - bi) { rem -= 32 - bi; ++bi; }
    const int bj = bi + rem;
    const int i0 = bi * 128, j0 = bj * 128;

    const int tid  = threadIdx.x;
    const int w    = tid >> 6;
    const int lane = tid & 63;
    const int wi   = (w & 1) * 64;       // wave's row quadrant
    const int wj   = (w >> 1) * 64;      // wave's col quadrant
    const int ln15 = lane & 15;
    const int lq   = lane >> 4;          // 0..3

    f32x4 acc[4][4] = {};                // [mt][nt], rows wi+mt*16+lq*4+rg, col wj+nt*16+ln15

    for (int k0 = 0; k0 < D; k0 += 32) {
        // --- stage A (rows i0..i0+127, k0..k0+31) and B (rows j0..) into LDS ---
        // LDS position s (16B granules) holds row r=s>>2, kgroup (s&3)^((r>>1)&3)  [XOR swizzle]
        #pragma unroll
        for (int p = 0; p < 2; ++p) {
            int s  = p * 256 + tid;
            int r  = s >> 2;
            int kg = (s & 3) ^ ((r >> 1) & 3);
            const _Float16* ga = e + (size_t)(i0 + r) * D + k0 + kg * 8;
            const _Float16* gb = e + (size_t)(j0 + r) * D + k0 + kg * 8;
            char* la = (char*)S + (p * 256 + w * 64) * 16;          // wave-uniform base
            char* lb = (char*)S + 8192 + (p * 256 + w * 64) * 16;
            gl2lds16(ga, la);
            gl2lds16(gb, lb);
        }
        __syncthreads();

        // --- fragments: A[m=ln15][k=lq*8+j], B[n=ln15][k=lq*8+j]; both row-major in LDS ---
        half8 af[4], bf[4];
        #pragma unroll
        for (int mt = 0; mt < 4; ++mt) {
            int r  = wi + mt * 16 + ln15;
            int kx = lq ^ ((r >> 1) & 3);
            af[mt] = *(const half8*)&S[r * 32 + kx * 8];
        }
        #pragma unroll
        for (int nt = 0; nt < 4; ++nt) {
            int r  = wj + nt * 16 + ln15;
            int kx = lq ^ ((r >> 1) & 3);
            bf[nt] = *(const half8*)&S[4096 + r * 32 + kx * 8];
        }
        #pragma unroll
        for (int mt = 0; mt < 4; ++mt)
            #pragma unroll
            for (int nt = 0; nt < 4; ++nt)
                acc[mt][nt] = __builtin_amdgcn_mfma_f32_16x16x32_f16(af[mt], bf[nt], acc[mt][nt], 0, 0, 0);
        __syncthreads();
    }

    // ---------------- epilogue: dist + dual-sided batch-hard mining ----------
    float sqi[4][4]; int labi[4][4];
    #pragma unroll
    for (int mt = 0; mt < 4; ++mt)
        #pragma unroll
        for (int rg = 0; rg < 4; ++rg) {
            int i = i0 + wi + mt * 16 + lq * 4 + rg;
            sqi[mt][rg] = sq[i];
            labi[mt][rg] = labels[i];
        }
    float sqj[4]; int labj[4];
    #pragma unroll
    for (int nt = 0; nt < 4; ++nt) {
        int j = j0 + wj + nt * 16 + ln15;
        sqj[nt] = sq[j];
        labj[nt] = labels[j];
    }

    float api[4][4], ani[4][4], apj[4], anj[4];
    #pragma unroll
    for (int mt = 0; mt < 4; ++mt)
        #pragma unroll
        for (int rg = 0; rg < 4; ++rg) { api[mt][rg] = -INFINITY; ani[mt][rg] = INFINITY; }
    #pragma unroll
    for (int nt = 0; nt < 4; ++nt) { apj[nt] = -INFINITY; anj[nt] = INFINITY; }

    #pragma unroll
    for (int nt = 0; nt < 4; ++nt) {
        int j = j0 + wj + nt * 16 + ln15;
        #pragma unroll
        for (int mt = 0; mt < 4; ++mt)
            #pragma unroll
            for (int rg = 0; rg < 4; ++rg) {
                int i = i0 + wi + mt * 16 + lq * 4 + rg;
                float d2 = sqi[mt][rg] + sqj[nt] - 2.0f * acc[mt][nt][rg];
                float dist = sqrtf(fmaxf(d2, 0.0f) + 1e-12f);
                if (labi[mt][rg] == labj[nt]) {
                    if (i != j) {
                        api[mt][rg] = fmaxf(api[mt][rg], dist);
                        apj[nt]     = fmaxf(apj[nt], dist);
                    }
                } else {
                    ani[mt][rg] = fminf(ani[mt][rg], dist);
                    anj[nt]     = fminf(anj[nt], dist);
                }
            }
    }

    // i-side: reduce over the 16 columns held by lanes differing in low 4 bits
    #pragma unroll
    for (int mt = 0; mt < 4; ++mt)
        #pragma unroll
        for (int rg = 0; rg < 4; ++rg) {
            float a_ = api[mt][rg], n_ = ani[mt][rg];
            #pragma unroll
            for (int off = 1; off < 16; off <<= 1) {
                a_ = fmaxf(a_, __shfl_xor(a_, off, 64));
                n_ = fminf(n_, __shfl_xor(n_, off, 64));
            }
            if (ln15 == 0) {
                int i = i0 + wi + mt * 16 + lq * 4 + rg;
                if (a_ > -1.0e37f) atomicMax(&ap_bits[i], __float_as_uint(a_));
                if (n_ <  1.0e37f) atomicMin(&an_bits[i], __float_as_uint(n_));
            }
        }

    // j-side (off-diagonal blocks only): reduce over rows = lanes differing in bits 4,5
    if (bi != bj) {
        #pragma unroll
        for (int nt = 0; nt < 4; ++nt) {
            float a_ = apj[nt], n_ = anj[nt];
            #pragma unroll
            for (int off = 16; off < 64; off <<= 1) {
                a_ = fmaxf(a_, __shfl_xor(a_, off, 64));
                n_ = fminf(n_, __shfl_xor(n_, off, 64));
            }
            if (lq == 0) {
                int j = j0 + wj + nt * 16 + ln15;
                if (a_ > -1.0e37f) atomicMax(&ap_bits[j], __float_as_uint(a_));
                if (n_ <  1.0e37f) atomicMin(&an_bits[j], __float_as_uint(n_));
            }
        }
    }
}

// ---------------- Kernel 3: finalize ----------------
__global__ __launch_bounds__(256) void finalize_kernel(const unsigned* __restrict__ ap_bits,
                                                       const unsigned* __restrict__ an_bits,
                                                       const int* __restrict__ labels,
                                                       float* __restrict__ out) {
    __shared__ int cnt[4];
    __shared__ float red[8];
    int tid = threadIdx.x;
    if (tid < 4) cnt[tid] = 0;
    __syncthreads();

    int local[4] = {0, 0, 0, 0};
    for (int i = tid; i < N; i += 256) local[labels[i] & 3]++;
    #pragma unroll
    for (int c = 0; c < 4; c++) atomicAdd(&cnt[c], local[c]);
    __syncthreads();

    float sum = 0.f, nv = 0.f;
    for (int i = tid; i < N; i += 256) {
        int l = labels[i] & 3;
        if (cnt[l] >= 2) {
            nv += 1.f;
            float apv = __uint_as_float(ap_bits[i]);
            float anv = __uint_as_float(an_bits[i]);
            if (anv < 3.0e38f) sum += fmaxf(apv - anv + MARGIN, 0.f);
        }
    }

    #pragma unroll
    for (int off = 32; off; off >>= 1) {
        sum += __shfl_down(sum, off, 64);
        nv  += __shfl_down(nv,  off, 64);
    }
    int w = tid >> 6;
    if ((tid & 63) == 0) { red[w] = sum; red[4 + w] = nv; }
    __syncthreads();
    if (tid == 0) {
        float s = red[0] + red[1] + red[2] + red[3];
        float n = red[4] + red[5] + red[6] + red[7];
        out[0] = s / fmaxf(n, 1.f);
    }
}

// ---------------- Launch ----------------
extern "C" void kernel_launch(void* const* d_in, const int* in_sizes, int n_in,
                              void* d_out, int out_size, void* d_ws, size_t ws_size,
                              hipStream_t stream) {
    const float* x = (const float*)d_in[0];
    const int* labels = (const int*)d_in[1];
    float* out = (float*)d_out;

    _Float16* e = (_Float16*)d_ws;
    float* sq = (float*)(e + (size_t)N * D);
    unsigned* ap_bits = (unsigned*)(sq + N);
    unsigned* an_bits = ap_bits + N;

    normalize_kernel<<<N, 256, 0, stream>>>(x, e, sq, ap_bits, an_bits);
    mine_kernel<<<528, 256, 0, stream>>>(e, sq, labels, ap_bits, an_bits);
    finalize_kernel<<<1, 256, 0, stream>>>(ap_bits, an_bits, labels, out);
}